// Round 10
// baseline (675.959 us; speedup 1.0000x reference)
//
#include <hip/hip_runtime.h>
#include <stdint.h>

#define N_ROWS 16384
#define DIM    512

typedef int v4i __attribute__((ext_vector_type(4)));
typedef unsigned long long u64;
typedef unsigned char u8;

// Async global->LDS, 16B per lane. LDS dest = wave-uniform base + lane*16.
__device__ __forceinline__ void gload_lds16(const void* g, void* l) {
    __builtin_amdgcn_global_load_lds(
        (const __attribute__((address_space(1))) unsigned int*)g,
        (__attribute__((address_space(3))) unsigned int*)l,
        16, 0, 0);
}

// ---------------- kernel 1: fp32 -> i8 quantize (+ table & out zero-init) ----------------
// r16-proven: i8 symmetric quantization, scale 20.0 (|q| <= ~110, no saturation).
// Argmax needs dot ORDER only; i8 512-dim dot noise < the fp8 noise that gave
// absmax 0.0 all session. i32 dots exact. Row-major, coalesced.
__global__ __launch_bounds__(256)
void convert_i8_kernel(const float* __restrict__ x, unsigned* __restrict__ x8,
                       u64* __restrict__ table, float* __restrict__ out) {
    int tid    = blockIdx.x * blockDim.x + threadIdx.x;
    int stride = gridDim.x * blockDim.x;
    if (tid == 0) *out = 0.f;
    if (tid < N_ROWS) table[tid] = 0;
    const float4* x4 = (const float4*)x;
    const int n4 = (N_ROWS * DIM) / 4;
    for (int i = tid; i < n4; i += stride) {
        float4 v = x4[i];
        int i0 = (int)rintf(fminf(fmaxf(v.x * 20.f, -127.f), 127.f));
        int i1 = (int)rintf(fminf(fmaxf(v.y * 20.f, -127.f), 127.f));
        int i2 = (int)rintf(fminf(fmaxf(v.z * 20.f, -127.f), 127.f));
        int i3 = (int)rintf(fminf(fmaxf(v.w * 20.f, -127.f), 127.f));
        x8[i] = (unsigned)(i0 & 255) | ((unsigned)(i1 & 255) << 8) |
                ((unsigned)(i2 & 255) << 16) | ((unsigned)(i3 & 255) << 24);
    }
}

// ---------------- kernel 2: symmetric tiled i8 GEMM + fused argmax ----------------
// r17: 256x128 tile, 512 threads / 8 waves (4 row-quarters x 2 col-halves) --
// SAME proven 2-barrier K-loop and per-wave fragment code as r16 (acc 4x4,
// operands 4+4 v4i -> VGPR ~84, pinned by __launch_bounds__(512,6)). Why:
// r16's 139.5us = 29us MFMA + ~110us staging/barrier/epilogue at only 10
// waves/CU. This shape: tiles 8256->4160 (barrier-drain per work halved),
// staged bytes x0.75 (B reuse doubled), occupancy -> 24 waves/CU (48KB LDS =
// 3 blocks/CU; 84 VGPR = 6 waves/SIMD). NOT the r9 trap: schedule unchanged,
// no double-buffer, no extra barriers, register footprint unchanged.
//
// Tile coverage (asymmetric fold, verified): row-blocks R in [0,64) of 256
// rows; col-blocks C in [0,128) of 128 cols; tiles {C >= 2R}. Count
// sum(128-2R) = 4160 = 32*130. Fold: g=bid/130, o=bid%130, lenTop=128-2g;
// o<lenTop -> (R,C)=(g,2g+o) else (63-g, 2(63-g)+o-lenTop).
// Every pair (i<j): j>>7 >= 2*(i>>8) -> covered by row-side (diag masked).
// Col-side (transpose) only when C >= 2R+2; C in {2R,2R+1} tiles' transpose
// region is covered by those same tiles' row-side (checked both directions).
//
// LDS 48KB: A = 256x128B (32KB), B = 128x128B (16KB), chunk swizzle
// kc = sk ^ (row&7) as always; staging 8-lane groups load full 128-B K-rounds
// coalesced; frag read = 1 ds_read_b128 per (rf|cf, s): chunk 4s+q of row
// (measured conflict-free in r16).
__global__ __launch_bounds__(512, 6)
void argmax_dots_kernel(const u8* __restrict__ xb, u64* __restrict__ table) {
    __shared__ __attribute__((aligned(16))) u8 ldsA[256 * 128];  // 32 KB
    __shared__ __attribute__((aligned(16))) u8 ldsB[128 * 128];  // 16 KB

    const int bid = blockIdx.x;
    const int g   = bid / 130;
    const int o   = bid % 130;
    const int lenTop = 128 - 2 * g;
    const int R = (o < lenTop) ? g : (63 - g);
    const int C = (o < lenTop) ? (2 * g + o) : (2 * (63 - g) + (o - lenTop));

    const int t      = threadIdx.x;      // [0,512)
    const int lane   = t & 63;
    const int wave   = t >> 6;           // [0,8)
    const int lane15 = lane & 15;
    const int quad   = lane >> 4;
    const int wr = wave >> 1;            // row quarter [0,4) of the 256-row tile
    const int wc = wave & 1;             // col half    {0,1} of the 128-col tile

    const int rowBase = R * 256;
    const int colBase = C * 128;

    // Staging sources: A = 4 issues (256 rows), B = 2 issues (128 rows).
    const u8* gA[4];
    const u8* gB[2];
#pragma unroll
    for (int j = 0; j < 4; ++j) {
        const int L   = j * 512 + t;
        const int row = L >> 3;
        const int kc  = (L & 7) ^ (row & 7);       // swizzled source chunk
        gA[j] = xb + (size_t)(rowBase + row) * DIM + kc * 16;
    }
#pragma unroll
    for (int j = 0; j < 2; ++j) {
        const int L   = j * 512 + t;
        const int row = L >> 3;
        const int kc  = (L & 7) ^ (row & 7);
        gB[j] = xb + (size_t)(colBase + row) * DIM + kc * 16;
    }
    const int dstOff = wave * 1024;      // + j*8192 per issue (bytes)

    // Per-lane frag addresses: row base + rf*2048 + xorS[s]
    const int aBase = (wr * 64 + lane15) * 128;
    const int bBase = (wc * 64 + lane15) * 128;
    int xorS[2];
#pragma unroll
    for (int s = 0; s < 2; ++s)
        xorS[s] = ((4 * s + quad) ^ (lane15 & 7)) << 4;

    v4i acc[4][4];
#pragma unroll
    for (int rf = 0; rf < 4; ++rf)
#pragma unroll
        for (int cf = 0; cf < 4; ++cf) {
            v4i z = {0, 0, 0, 0};
            acc[rf][cf] = z;
        }

#pragma unroll
    for (int k = 0; k < 4; ++k) {           // 4 K-rounds of BK=128
        const int kk = k * 128;             // byte offset within a row
#pragma unroll
        for (int j = 0; j < 4; ++j)
            gload_lds16(gA[j] + kk, (char*)ldsA + j * 8192 + dstOff);
#pragma unroll
        for (int j = 0; j < 2; ++j)
            gload_lds16(gB[j] + kk, (char*)ldsB + j * 8192 + dstOff);
        __syncthreads();                    // drains vmcnt; loads visible

#pragma unroll
        for (int s = 0; s < 2; ++s) {       // 2 k-steps of 64 i8
            const int xs = xorS[s];
            v4i a4[4], b4[4];
#pragma unroll
            for (int rf = 0; rf < 4; ++rf)
                a4[rf] = *(const v4i*)(ldsA + aBase + rf * 2048 + xs);
#pragma unroll
            for (int cf = 0; cf < 4; ++cf)
                b4[cf] = *(const v4i*)(ldsB + bBase + cf * 2048 + xs);
#pragma unroll
            for (int rf = 0; rf < 4; ++rf)
#pragma unroll
                for (int cf = 0; cf < 4; ++cf)
                    acc[rf][cf] = __builtin_amdgcn_mfma_i32_16x16x64_i8(
                        a4[rf], b4[cf], acc[rf][cf], 0, 0, 0);
        }
        __syncthreads();                    // protect LDS from next round's writes
    }

    // ---- epilogue: row-side argmax (C/D layout: col=lane15+16*cf, row=quad*4+e) ----
    // i32 dots exact; monotonic u32 key = dot ^ 0x80000000.
    const int colLane = colBase + wc * 64 + lane15;
#pragma unroll
    for (int rf = 0; rf < 4; ++rf) {
#pragma unroll
        for (int e = 0; e < 4; ++e) {
            const int row = rowBase + wr * 64 + rf * 16 + quad * 4 + e;
            int bv = (int)0x80000000;       // INT_MIN
            int bc = 0;
#pragma unroll
            for (int cf = 0; cf < 4; ++cf) {
                const int v = acc[rf][cf][e];
                const int col = colLane + cf * 16;
                if (v > bv && col != row) { bv = v; bc = col; }
            }
            u64 packed = ((u64)(unsigned)(bv ^ (int)0x80000000) << 32)
                       | (unsigned)(~bc);   // ~col: ties->lowest idx
#pragma unroll
            for (int m = 1; m < 16; m <<= 1) {
                u64 o2 = __shfl_xor(packed, m, 64);
                if (o2 > packed) packed = o2;
            }
            if (lane15 == 0) atomicMax(&table[row], packed);
        }
    }

    // ---- epilogue: col-side (transposed) argmax; skipped when the tile's
    // transpose region is already covered by this row-block's own row-side
    // (C in {2R, 2R+1}), which also keeps the diagonal masked. ----
    if (C >= 2 * R + 2) {
#pragma unroll
        for (int cf = 0; cf < 4; ++cf) {
            const int col = colLane + cf * 16;
            int bv  = (int)0x80000000;
            int br_ = 0;
#pragma unroll
            for (int rf = 0; rf < 4; ++rf)
#pragma unroll
                for (int e = 0; e < 4; ++e) {
                    const int v = acc[rf][cf][e];
                    const int row = rowBase + wr * 64 + rf * 16 + quad * 4 + e;
                    if (v > bv) { bv = v; br_ = row; }
                }
            u64 packed = ((u64)(unsigned)(bv ^ (int)0x80000000) << 32)
                       | (unsigned)(~br_);
            u64 o2 = __shfl_xor(packed, 16, 64); if (o2 > packed) packed = o2;
            o2     = __shfl_xor(packed, 32, 64); if (o2 > packed) packed = o2;
            if (quad == 0) atomicMax(&table[col], packed);
        }
    }
}

// ---------------- kernel 3: rho + loss epilogue (fp32 exact) ----------------
// r13-proven: 512 blocks x 8 rows/wave, table prefetch, block-level LDS
// reduction -> 512 same-address atomics (4096 atomics cost +20 us of tail).
__global__ __launch_bounds__(256)
void rho_loss_kernel(const float* __restrict__ x, const u64* __restrict__ table,
                     float* __restrict__ out) {
    __shared__ float partial[4];
    const int lane = threadIdx.x & 63;
    const int wave = threadIdx.x >> 6;
    const int waveGlobal = blockIdx.x * 4 + wave;   // 2048 waves

    u64 pk[8];
#pragma unroll
    for (int r8 = 0; r8 < 8; ++r8) pk[r8] = table[waveGlobal * 8 + r8];

    float local = 0.f;
#pragma unroll
    for (int r8 = 0; r8 < 8; ++r8) {
        const int row = waveGlobal * 8 + r8;
        const int nb  = (int)(~(unsigned)(pk[r8] & 0xFFFFFFFFu));

        const float4* xr = (const float4*)(x + (size_t)row * DIM);
        const float4* xn = (const float4*)(x + (size_t)nb  * DIM);
        float s = 0.f;
#pragma unroll
        for (int tt = 0; tt < 2; ++tt) {
            float4 a = xr[lane * 2 + tt];
            float4 b = xn[lane * 2 + tt];
            float d0 = a.x - b.x + 1e-6f;
            float d1 = a.y - b.y + 1e-6f;
            float d2 = a.z - b.z + 1e-6f;
            float d3 = a.w - b.w + 1e-6f;
            s += d0 * d0 + d1 * d1 + d2 * d2 + d3 * d3;
        }
#pragma unroll
        for (int m = 1; m < 64; m <<= 1) s += __shfl_xor(s, m, 64);

        if (lane == 0) {
            float rho = sqrtf(s);
            local += logf(rho + 1e-8f);
        }
    }
    if (lane == 0) partial[wave] = local;
    __syncthreads();
    if (threadIdx.x == 0) {
        const float s = partial[0] + partial[1] + partial[2] + partial[3];
        atomicAdd(out, -s * (1.0f / 16384.0f));
    }
}

extern "C" void kernel_launch(void* const* d_in, const int* in_sizes, int n_in,
                              void* d_out, int out_size, void* d_ws, size_t ws_size,
                              hipStream_t stream) {
    const float* x = (const float*)d_in[0];

    // Workspace: [0, 8 MiB) i8 x (row-major); then 16384 x u64 argmax table.
    u8*    xb    = (u8*)d_ws;
    u64*   table = (u64*)((char*)d_ws + (size_t)N_ROWS * DIM);
    float* out   = (float*)d_out;

    convert_i8_kernel<<<2048, 256, 0, stream>>>(x, (unsigned*)xb, table, out);
    argmax_dots_kernel<<<4160, 512, 0, stream>>>(xb, table);
    rho_loss_kernel<<<512, 256, 0, stream>>>(x, table, out);
}

// Round 11
// 228.054 us; speedup vs baseline: 2.9640x; 2.9640x over previous
//
#include <hip/hip_runtime.h>
#include <stdint.h>

#define N_ROWS 16384
#define DIM    512

typedef int v4i __attribute__((ext_vector_type(4)));
typedef unsigned long long u64;
typedef unsigned char u8;

// Async global->LDS, 16B per lane. LDS dest = wave-uniform base + lane*16.
__device__ __forceinline__ void gload_lds16(const void* g, void* l) {
    __builtin_amdgcn_global_load_lds(
        (const __attribute__((address_space(1))) unsigned int*)g,
        (__attribute__((address_space(3))) unsigned int*)l,
        16, 0, 0);
}

// ---------------- kernel 1: fp32 -> i8 quantize (+ table & out zero-init) ----------------
// r16-proven: i8 symmetric quantization, scale 20.0 (|q| <= ~110, no saturation).
// Argmax needs dot ORDER only; i8 512-dim dot noise < the fp8 noise that gave
// absmax 0.0 all session. i32 dots exact. Row-major, coalesced.
__global__ __launch_bounds__(256)
void convert_i8_kernel(const float* __restrict__ x, unsigned* __restrict__ x8,
                       u64* __restrict__ table, float* __restrict__ out) {
    int tid    = blockIdx.x * blockDim.x + threadIdx.x;
    int stride = gridDim.x * blockDim.x;
    if (tid == 0) *out = 0.f;
    if (tid < N_ROWS) table[tid] = 0;
    const float4* x4 = (const float4*)x;
    const int n4 = (N_ROWS * DIM) / 4;
    for (int i = tid; i < n4; i += stride) {
        float4 v = x4[i];
        int i0 = (int)rintf(fminf(fmaxf(v.x * 20.f, -127.f), 127.f));
        int i1 = (int)rintf(fminf(fmaxf(v.y * 20.f, -127.f), 127.f));
        int i2 = (int)rintf(fminf(fmaxf(v.z * 20.f, -127.f), 127.f));
        int i3 = (int)rintf(fminf(fmaxf(v.w * 20.f, -127.f), 127.f));
        x8[i] = (unsigned)(i0 & 255) | ((unsigned)(i1 & 255) << 8) |
                ((unsigned)(i2 & 255) << 16) | ((unsigned)(i3 & 255) << 24);
    }
}

// ---------------- kernel 2: symmetric tiled i8 GEMM + fused argmax ----------------
// MEASURED OPTIMUM (r16: argmax 139.5us, total 220us; MfmaUtil 20.9 /
// VALUBusy 43.2 / occ 32 / conflicts 0 / VGPR 84). 128^2 tile, 4 waves,
// BK=128, 2-barrier K-loop, mfma_i32_16x16x64_i8 (1.93x fp8 rate).
// Refuted alternatives (all measured this session):
//  * r9  8-wave 256^2 phase-split w/ counted vmcnt: 233us (coarse-split trap
//    + 1 block/CU occupancy).
//  * r10 MX-scaled K=128 MFMA: 316us (+64 live VGPR -> occupancy collapse).
//  * r12 cooperative 3-phase fusion: container failure (harness).
//  * r15 conflict-free b64 layout: 174us -- conflicts are NOT on the critical
//    path (issue/VALU-bound); 2-way b128 aliasing is free.
//  * r17 256x128 tile + __launch_bounds__(512,6): VGPR pinned to 40 -> acc
//    spilled to scratch (FETCH 41MB -> 974MB), 600us. AGPRs share the unified
//    file; bigger tiles cannot raise occupancy at this register footprint.
// LDS (16 KB/matrix): 128 rows x 8 chunks of 16 B; slot(row,sk) holds chunk
// kc = sk ^ (row&7); staging 8-lane groups load full 128-B rows coalesced.
// Frag read (k-step s, quad q, lane15 l): chunk 4s+q of row rf*16+l -> one
// ds_read_b128 at row*128 + ((4s+q)^(l&7))*16 (measured conflict-free).
__global__ __launch_bounds__(256)
void argmax_dots_kernel(const u8* __restrict__ xb, u64* __restrict__ table) {
    __shared__ __attribute__((aligned(16))) u8 ldsA[128 * 128];  // 16 KB
    __shared__ __attribute__((aligned(16))) u8 ldsB[128 * 128];  // 16 KB

    const int u = blockIdx.x >> 6;
    const int p = blockIdx.x & 63;
    const int rT = (u <= p) ? (127 - p) : p;
    const int cT = (u <= p) ? (127 - u) : (u - 1);

    const int t      = threadIdx.x;
    const int lane   = t & 63;
    const int wave   = t >> 6;
    const int lane15 = lane & 15;
    const int quad   = lane >> 4;
    const int rh = wave >> 1;               // row half of the 128x128 tile
    const int ch = wave & 1;                // col half

    const int rowBase = rT * 128;
    const int colBase = cT * 128;

    // Staging sources: 4 issues per matrix per round, coalesced row-major.
    const u8* gA[4];
    const u8* gB[4];
#pragma unroll
    for (int j = 0; j < 4; ++j) {
        const int L   = j * 256 + t;
        const int row = L >> 3;
        const int kc  = (L & 7) ^ (row & 7);       // swizzled source chunk
        gA[j] = xb + (size_t)(rowBase + row) * DIM + kc * 16;
        gB[j] = xb + (size_t)(colBase + row) * DIM + kc * 16;
    }
    const int dstOff = wave * 1024;         // + j*4096 per issue (bytes)

    // Per-lane frag addresses: row base + rf*2048 + xorS[s]
    const int aBase = (rh * 64 + lane15) * 128;
    const int bBase = (ch * 64 + lane15) * 128;
    int xorS[2];
#pragma unroll
    for (int s = 0; s < 2; ++s)
        xorS[s] = ((4 * s + quad) ^ (lane15 & 7)) << 4;

    v4i acc[4][4];
#pragma unroll
    for (int rf = 0; rf < 4; ++rf)
#pragma unroll
        for (int cf = 0; cf < 4; ++cf) {
            v4i z = {0, 0, 0, 0};
            acc[rf][cf] = z;
        }

#pragma unroll
    for (int k = 0; k < 4; ++k) {           // 4 K-rounds of BK=128
        const int kk = k * 128;             // byte offset within a row
#pragma unroll
        for (int j = 0; j < 4; ++j) {
            gload_lds16(gA[j] + kk, (char*)ldsA + j * 4096 + dstOff);
            gload_lds16(gB[j] + kk, (char*)ldsB + j * 4096 + dstOff);
        }
        __syncthreads();                    // drains vmcnt; loads visible

#pragma unroll
        for (int s = 0; s < 2; ++s) {       // 2 k-steps of 64 i8
            const int xs = xorS[s];
            v4i a4[4], b4[4];
#pragma unroll
            for (int rf = 0; rf < 4; ++rf)
                a4[rf] = *(const v4i*)(ldsA + aBase + rf * 2048 + xs);
#pragma unroll
            for (int cf = 0; cf < 4; ++cf)
                b4[cf] = *(const v4i*)(ldsB + bBase + cf * 2048 + xs);
#pragma unroll
            for (int rf = 0; rf < 4; ++rf)
#pragma unroll
                for (int cf = 0; cf < 4; ++cf)
                    acc[rf][cf] = __builtin_amdgcn_mfma_i32_16x16x64_i8(
                        a4[rf], b4[cf], acc[rf][cf], 0, 0, 0);
        }
        __syncthreads();                    // protect LDS from next round's writes
    }

    // ---- epilogue: row-side argmax (C/D layout: col=lane15+16*cf, row=quad*4+e) ----
    // i32 dots are exact; monotonic u32 key = dot ^ 0x80000000.
    const int colLane = colBase + ch * 64 + lane15;
#pragma unroll
    for (int rf = 0; rf < 4; ++rf) {
#pragma unroll
        for (int e = 0; e < 4; ++e) {
            const int row = rowBase + rh * 64 + rf * 16 + quad * 4 + e;
            int bv = (int)0x80000000;       // INT_MIN
            int bc = 0;
#pragma unroll
            for (int cf = 0; cf < 4; ++cf) {
                const int v = acc[rf][cf][e];
                const int col = colLane + cf * 16;
                if (v > bv && col != row) { bv = v; bc = col; }
            }
            u64 packed = ((u64)(unsigned)(bv ^ (int)0x80000000) << 32)
                       | (unsigned)(~bc);   // ~col: ties->lowest idx
#pragma unroll
            for (int m = 1; m < 16; m <<= 1) {
                u64 o = __shfl_xor(packed, m, 64);
                if (o > packed) packed = o;
            }
            if (lane15 == 0) atomicMax(&table[row], packed);
        }
    }

    // ---- epilogue: col-side (transposed) argmax for off-diagonal tiles ----
    if (rT != cT) {
#pragma unroll
        for (int cf = 0; cf < 4; ++cf) {
            const int col = colLane + cf * 16;
            int bv  = (int)0x80000000;
            int br_ = 0;
#pragma unroll
            for (int rf = 0; rf < 4; ++rf)
#pragma unroll
                for (int e = 0; e < 4; ++e) {
                    const int v = acc[rf][cf][e];
                    const int row = rowBase + rh * 64 + rf * 16 + quad * 4 + e;
                    if (v > bv) { bv = v; br_ = row; }
                }
            u64 packed = ((u64)(unsigned)(bv ^ (int)0x80000000) << 32)
                       | (unsigned)(~br_);
            u64 o = __shfl_xor(packed, 16, 64); if (o > packed) packed = o;
            o     = __shfl_xor(packed, 32, 64); if (o > packed) packed = o;
            if (quad == 0) atomicMax(&table[col], packed);
        }
    }
}

// ---------------- kernel 3: rho + loss epilogue (fp32 exact) ----------------
// r13-proven: 512 blocks x 8 rows/wave, table prefetch, block-level LDS
// reduction -> 512 same-address atomics (4096 atomics cost +20 us of tail).
__global__ __launch_bounds__(256)
void rho_loss_kernel(const float* __restrict__ x, const u64* __restrict__ table,
                     float* __restrict__ out) {
    __shared__ float partial[4];
    const int lane = threadIdx.x & 63;
    const int wave = threadIdx.x >> 6;
    const int waveGlobal = blockIdx.x * 4 + wave;   // 2048 waves

    u64 pk[8];
#pragma unroll
    for (int r8 = 0; r8 < 8; ++r8) pk[r8] = table[waveGlobal * 8 + r8];

    float local = 0.f;
#pragma unroll
    for (int r8 = 0; r8 < 8; ++r8) {
        const int row = waveGlobal * 8 + r8;
        const int nb  = (int)(~(unsigned)(pk[r8] & 0xFFFFFFFFu));

        const float4* xr = (const float4*)(x + (size_t)row * DIM);
        const float4* xn = (const float4*)(x + (size_t)nb  * DIM);
        float s = 0.f;
#pragma unroll
        for (int tt = 0; tt < 2; ++tt) {
            float4 a = xr[lane * 2 + tt];
            float4 b = xn[lane * 2 + tt];
            float d0 = a.x - b.x + 1e-6f;
            float d1 = a.y - b.y + 1e-6f;
            float d2 = a.z - b.z + 1e-6f;
            float d3 = a.w - b.w + 1e-6f;
            s += d0 * d0 + d1 * d1 + d2 * d2 + d3 * d3;
        }
#pragma unroll
        for (int m = 1; m < 64; m <<= 1) s += __shfl_xor(s, m, 64);

        if (lane == 0) {
            float rho = sqrtf(s);
            local += logf(rho + 1e-8f);
        }
    }
    if (lane == 0) partial[wave] = local;
    __syncthreads();
    if (threadIdx.x == 0) {
        const float s = partial[0] + partial[1] + partial[2] + partial[3];
        atomicAdd(out, -s * (1.0f / 16384.0f));
    }
}

extern "C" void kernel_launch(void* const* d_in, const int* in_sizes, int n_in,
                              void* d_out, int out_size, void* d_ws, size_t ws_size,
                              hipStream_t stream) {
    const float* x = (const float*)d_in[0];

    // Workspace: [0, 8 MiB) i8 x (row-major); then 16384 x u64 argmax table.
    u8*    xb    = (u8*)d_ws;
    u64*   table = (u64*)((char*)d_ws + (size_t)N_ROWS * DIM);
    float* out   = (float*)d_out;

    convert_i8_kernel<<<2048, 256, 0, stream>>>(x, (unsigned*)xb, table, out);
    argmax_dots_kernel<<<8256, 256, 0, stream>>>(xb, table);
    rho_loss_kernel<<<512, 256, 0, stream>>>(x, table, out);
}